// Round 3
// baseline (175.061 us; speedup 1.0000x reference)
//
#include <hip/hip_runtime.h>

typedef __bf16 bf16;
typedef __attribute__((ext_vector_type(8))) __bf16 bf16x8;
typedef __attribute__((ext_vector_type(4))) float f32x4;

#define SEQ 2048
#define EMB 1024
#define NH  16
#define DH  64

// ---------------- conversion kernels ----------------

__global__ __launch_bounds__(256) void conv_f32_bf16(const float* __restrict__ in,
                                                     bf16* __restrict__ out, int n8) {
    int i = blockIdx.x * blockDim.x + threadIdx.x;
    if (i >= n8) return;
    float4 a = ((const float4*)in)[2 * i];
    float4 b = ((const float4*)in)[2 * i + 1];
    bf16x8 o;
    o[0] = (bf16)a.x; o[1] = (bf16)a.y; o[2] = (bf16)a.z; o[3] = (bf16)a.w;
    o[4] = (bf16)b.x; o[5] = (bf16)b.y; o[6] = (bf16)b.z; o[7] = (bf16)b.w;
    ((bf16x8*)out)[i] = o;
}

// out[C][R] = (bf16) in[R][C]
__global__ __launch_bounds__(256) void transpose_f32_bf16(const float* __restrict__ in,
                                                          bf16* __restrict__ out,
                                                          int R, int C) {
    __shared__ float t[32][33];
    int tx = threadIdx.x & 31, ty = threadIdx.x >> 5;  // 32 x 8
    int c0 = blockIdx.x * 32, r0 = blockIdx.y * 32;
#pragma unroll
    for (int s = 0; s < 4; s++) {
        int row = ty + s * 8;
        t[row][tx] = in[(size_t)(r0 + row) * C + c0 + tx];
    }
    __syncthreads();
#pragma unroll
    for (int s = 0; s < 4; s++) {
        int row = ty + s * 8;
        out[(size_t)(c0 + row) * R + r0 + tx] = (bf16)t[tx][row];
    }
}

// ---------------- GEMM core (128x128, BK=32, double-buffered, swizzled) ----------------

#define BM 128
#define BN 128
#define BK 32

__device__ __forceinline__ void gload16(const bf16* g, bf16* l) {
    __builtin_amdgcn_global_load_lds((__attribute__((address_space(1))) void*)(void*)g,
                                     (__attribute__((address_space(3))) void*)l, 16, 0, 0);
}

// stage a 128x32 bf16 tile; LDS dest linear (lane*16B within 1KB chunks);
// source col pre-swizzled: G[row][slot ^ (row&3)] lands at LDS[row][slot].
__device__ __forceinline__ void stage_tile(const bf16* src, int ld, int row0, int k0,
                                           bf16* lds, int wave, int lane) {
#pragma unroll
    for (int c = 0; c < 2; c++) {
        int chunk = wave + 4 * c;                 // 0..7, wave-uniform
        int row = chunk * 16 + (lane >> 2);
        int slot = (lane & 3) ^ ((lane >> 2) & 3);
        const bf16* g = src + (size_t)(row0 + row) * ld + k0 + slot * 8;
        gload16(g, lds + chunk * 512);
    }
}

// frag read: lane holds T[row=base+(l&15)][k=(l>>4)*8+i]; stored slot = s ^ (row&3)
__device__ __forceinline__ bf16x8 frag(const bf16* lds, int row, int s) {
    int slot = s ^ (row & 3);
    return *(const bf16x8*)&lds[row * BK + slot * 8];
}

// double-buffered main loop: stage(next) -> ds_read+MFMA(cur) -> vmcnt(0)+barrier
__device__ __forceinline__ void gemm_mainloop(const bf16* A, const bf16* Bt, int Kdim,
                                              int m0, int n0, bf16* As, bf16* Bs,
                                              int wave, int lane, int wr, int wc,
                                              f32x4 acc[4][4]) {
    stage_tile(A, Kdim, m0, 0, As, wave, lane);
    stage_tile(Bt, Kdim, n0, 0, Bs, wave, lane);
    asm volatile("s_waitcnt vmcnt(0)" ::: "memory");
    __builtin_amdgcn_s_barrier();

    int cur = 0;
    const int iters = Kdim / BK;
    for (int it = 0; it < iters; ++it) {
        if (it + 1 < iters) {
            stage_tile(A, Kdim, m0, (it + 1) * BK, As + (cur ^ 1) * BM * BK, wave, lane);
            stage_tile(Bt, Kdim, n0, (it + 1) * BK, Bs + (cur ^ 1) * BN * BK, wave, lane);
        }
        const bf16* as = As + cur * BM * BK;
        const bf16* bs = Bs + cur * BN * BK;
        int s = lane >> 4;
        bf16x8 a[4], b[4];
#pragma unroll
        for (int i = 0; i < 4; i++)
            a[i] = frag(as, wr * 64 + i * 16 + (lane & 15), s);
#pragma unroll
        for (int j = 0; j < 4; j++)
            b[j] = frag(bs, wc * 64 + j * 16 + (lane & 15), s);
#pragma unroll
        for (int i = 0; i < 4; i++)
#pragma unroll
            for (int j = 0; j < 4; j++)
                acc[i][j] = __builtin_amdgcn_mfma_f32_16x16x32_bf16(a[i], b[j], acc[i][j], 0, 0, 0);
        asm volatile("s_waitcnt vmcnt(0)" ::: "memory");
        __builtin_amdgcn_s_barrier();
        cur ^= 1;
    }
}

// QKV projection: C[m][col] -> de-interleave col = hh*192 + dd*3 + which
__global__ __launch_bounds__(256) void gemm_qkv(const bf16* __restrict__ A,
                                                const bf16* __restrict__ Bt,
                                                const float* __restrict__ bias,
                                                bf16* __restrict__ Qb, bf16* __restrict__ Kb,
                                                bf16* __restrict__ Vt) {
    __shared__ alignas(16) bf16 As[2 * BM * BK];
    __shared__ alignas(16) bf16 Bs[2 * BN * BK];
    int wave = threadIdx.x >> 6, lane = threadIdx.x & 63;
    int wr = wave >> 1, wc = wave & 1;
    int m0 = blockIdx.y * BM, n0 = blockIdx.x * BN;
    f32x4 acc[4][4] = {};
    gemm_mainloop(A, Bt, EMB, m0, n0, As, Bs, wave, lane, wr, wc, acc);

    int m_base = m0 + wr * 64;
    int n_base = n0 + wc * 64;
#pragma unroll
    for (int i = 0; i < 4; i++) {
#pragma unroll
        for (int j = 0; j < 4; j++) {
            int col = n_base + j * 16 + (lane & 15);
            float bv = bias[col];
            int hh = col / 192;
            int rem = col - hh * 192;
            int dd = rem / 3;
            int which = rem - dd * 3;
#pragma unroll
            for (int r = 0; r < 4; r++) {
                int row = m_base + i * 16 + 4 * (lane >> 4) + r;
                int bb = row >> 11, npos = row & 2047;
                float v = acc[i][j][r] + bv;
                size_t bh = (size_t)bb * NH + hh;
                if (which == 0)
                    Qb[(bh * SEQ + npos) * DH + dd] = (bf16)(v * 0.03125f);  // fold 1/sqrt(1024)
                else if (which == 1)
                    Kb[(bh * SEQ + npos) * DH + dd] = (bf16)v;
                else
                    Vt[(bh * DH + dd) * SEQ + npos] = (bf16)v;               // V transposed [d][n]
            }
        }
    }
}

// proj: fp32 out + bias
__global__ __launch_bounds__(256) void gemm_proj(const bf16* __restrict__ A,
                                                 const bf16* __restrict__ Bt,
                                                 const float* __restrict__ bias,
                                                 float* __restrict__ C) {
    __shared__ alignas(16) bf16 As[2 * BM * BK];
    __shared__ alignas(16) bf16 Bs[2 * BN * BK];
    int wave = threadIdx.x >> 6, lane = threadIdx.x & 63;
    int wr = wave >> 1, wc = wave & 1;
    int m0 = blockIdx.y * BM, n0 = blockIdx.x * BN;
    f32x4 acc[4][4] = {};
    gemm_mainloop(A, Bt, EMB, m0, n0, As, Bs, wave, lane, wr, wc, acc);

    int m_base = m0 + wr * 64;
    int n_base = n0 + wc * 64;
#pragma unroll
    for (int i = 0; i < 4; i++) {
#pragma unroll
        for (int j = 0; j < 4; j++) {
            int col = n_base + j * 16 + (lane & 15);
            float bv = bias[col];
#pragma unroll
            for (int r = 0; r < 4; r++) {
                int row = m_base + i * 16 + 4 * (lane >> 4) + r;
                C[(size_t)row * EMB + col] = acc[i][j][r] + bv;
            }
        }
    }
}

// ---------------- attention ----------------
// Q,K: [bh][n][d] bf16 (Q pre-scaled); Vt: [bh][d][n] bf16; O: [b][n][e] bf16
// 4 waves/block, 32 q-rows/wave (128/block), KV tile 64 double-buffered in LDS.

// stage one 64-row x 128B tile; rows strided ldElems in global.
__device__ __forceinline__ void stage64(const bf16* gbase, int ldElems, bf16* lds,
                                        int wave, int lane) {
#pragma unroll
    for (int i = 0; i < 2; i++) {
        int c = wave * 2 + i;                       // 0..7 chunks of 1KB
        int row = c * 8 + (lane >> 3);
        int colb = (((lane & 7) ^ (lane >> 3)) << 4);   // inverse-swizzled source col
        const bf16* g = gbase + (size_t)row * ldElems + (colb >> 1);
        gload16(g, lds + c * 512);
    }
}

__global__ __launch_bounds__(256) void attn(const bf16* __restrict__ Q,
                                            const bf16* __restrict__ K,
                                            const bf16* __restrict__ Vt,
                                            bf16* __restrict__ O) {
    // XCD-aware swizzle: 512 blocks, 8 XCDs -> 64-block chunks = 4 bh per XCD
    int flat = blockIdx.x;
    int swz = (flat & 7) * 64 + (flat >> 3);
    int bh = swz >> 4;          // 16 q-blocks per bh
    int qb = swz & 15;

    int wave = threadIdx.x >> 6, lane = threadIdx.x & 63;
    int wq0 = qb * 128 + wave * 32;
    const bf16* Qg = Q + (size_t)bh * SEQ * DH;
    const bf16* Kg = K + (size_t)bh * SEQ * DH;
    const bf16* Vg = Vt + (size_t)bh * DH * SEQ;

    __shared__ alignas(16) bf16 Ks[2][64 * 64];
    __shared__ alignas(16) bf16 Vs[2][64 * 64];
    __shared__ alignas(16) bf16 Pl[4][32 * 64];
    char* pb = (char*)&Pl[wave][0];

    // Q fragments: qf[qt][ds], lane holds Q[wq0+qt*16+(l&15)][ds*32+(l>>4)*8 ..+7]
    bf16x8 qf[2][2];
#pragma unroll
    for (int qt = 0; qt < 2; qt++)
#pragma unroll
        for (int ds = 0; ds < 2; ds++)
            qf[qt][ds] = *(const bf16x8*)(Qg + (size_t)(wq0 + qt * 16 + (lane & 15)) * DH +
                                          ds * 32 + (lane >> 4) * 8);

    f32x4 Oc[2][4] = {};
    float lsum[2][4] = {};

    // prologue: stage tile 0
    stage64(Kg, DH, &Ks[0][0], wave, lane);
    stage64(Vg, SEQ, &Vs[0][0], wave, lane);
    asm volatile("s_waitcnt vmcnt(0)" ::: "memory");
    __builtin_amdgcn_s_barrier();

    int cur = 0;
    for (int it = 0; it < SEQ / 64; ++it) {
        if (it + 1 < SEQ / 64) {
            stage64(Kg + (size_t)(it + 1) * 64 * DH, DH, &Ks[cur ^ 1][0], wave, lane);
            stage64(Vg + (size_t)(it + 1) * 64, SEQ, &Vs[cur ^ 1][0], wave, lane);
        }
        const char* kc = (const char*)&Ks[cur][0];
        const char* vc = (const char*)&Vs[cur][0];

        // K fragments (shared across both q-tiles): kf[t][ds]
        bf16x8 kf[4][2];
#pragma unroll
        for (int t = 0; t < 4; t++)
#pragma unroll
            for (int ds = 0; ds < 2; ds++) {
                int row = 16 * t + (lane & 15);
                int slot = (ds * 4 + (lane >> 4)) ^ (row & 7);
                kf[t][ds] = *(const bf16x8*)(kc + row * 128 + slot * 16);
            }

        // S = Q K^T, P = exp(S) -> swizzled LDS
#pragma unroll
        for (int qt = 0; qt < 2; qt++) {
#pragma unroll
            for (int t = 0; t < 4; t++) {
                f32x4 acc = {};
#pragma unroll
                for (int ds = 0; ds < 2; ds++)
                    acc = __builtin_amdgcn_mfma_f32_16x16x32_bf16(qf[qt][ds], kf[t][ds], acc, 0, 0, 0);
#pragma unroll
                for (int r = 0; r < 4; r++) {
                    float p = __expf(acc[r]);
                    lsum[qt][r] += p;
                    int prow = qt * 16 + 4 * (lane >> 4) + r;
                    int off = (prow * 128 + (16 * t + (lane & 15)) * 2) ^ ((prow & 7) << 4);
                    *(bf16*)(pb + off) = (bf16)p;
                }
            }
        }

        // P A-fragments
        bf16x8 pa[2][2];
#pragma unroll
        for (int qt = 0; qt < 2; qt++)
#pragma unroll
            for (int ms = 0; ms < 2; ms++) {
                int prow = qt * 16 + (lane & 15);
                int slot = (ms * 4 + (lane >> 4)) ^ (prow & 7);
                pa[qt][ms] = *(const bf16x8*)(pb + prow * 128 + slot * 16);
            }

        // O += P @ V
#pragma unroll
        for (int dt = 0; dt < 4; dt++)
#pragma unroll
            for (int ms = 0; ms < 2; ms++) {
                int vrow = 16 * dt + (lane & 15);
                int slot = (ms * 4 + (lane >> 4)) ^ (vrow & 7);
                bf16x8 vf = *(const bf16x8*)(vc + vrow * 128 + slot * 16);
#pragma unroll
                for (int qt = 0; qt < 2; qt++)
                    Oc[qt][dt] = __builtin_amdgcn_mfma_f32_16x16x32_bf16(pa[qt][ms], vf, Oc[qt][dt], 0, 0, 0);
            }

        asm volatile("s_waitcnt vmcnt(0)" ::: "memory");
        __builtin_amdgcn_s_barrier();
        cur ^= 1;
    }

    // row sums across the 16-lane column groups
#pragma unroll
    for (int qt = 0; qt < 2; qt++)
#pragma unroll
        for (int r = 0; r < 4; r++) {
            float s = lsum[qt][r];
            s += __shfl_xor(s, 1);
            s += __shfl_xor(s, 2);
            s += __shfl_xor(s, 4);
            s += __shfl_xor(s, 8);
            lsum[qt][r] = 1.0f / s;
        }
    int bb = bh >> 4, hh = bh & 15;
#pragma unroll
    for (int qt = 0; qt < 2; qt++)
#pragma unroll
        for (int dt = 0; dt < 4; dt++)
#pragma unroll
            for (int r = 0; r < 4; r++) {
                int row = wq0 + qt * 16 + 4 * (lane >> 4) + r;
                O[((size_t)bb * SEQ + row) * EMB + hh * DH + dt * 16 + (lane & 15)] =
                    (bf16)(Oc[qt][dt][r] * lsum[qt][r]);
            }
}

// ---------------- launch ----------------

extern "C" void kernel_launch(void* const* d_in, const int* in_sizes, int n_in,
                              void* d_out, int out_size, void* d_ws, size_t ws_size,
                              hipStream_t stream) {
    const float* x     = (const float*)d_in[0];
    const float* Wqkv  = (const float*)d_in[1];
    const float* bqkv  = (const float*)d_in[2];
    const float* Wproj = (const float*)d_in[3];
    const float* bproj = (const float*)d_in[4];
    float* out = (float*)d_out;
    char* ws = (char*)d_ws;

    bf16* xb     = (bf16*)(ws + 0);          //  8 MB [4096][1024]
    bf16* attO   = xb;                       //  aliased: xb dead after gemm_qkv
    bf16* WqkvT  = (bf16*)(ws + 8388608);    //  6 MB [3072][1024]
    bf16* WprojT = (bf16*)(ws + 14680064);   //  2 MB [1024][1024]
    bf16* Qb     = (bf16*)(ws + 16777216);   //  8 MB [32][2048][64]
    bf16* Kb     = (bf16*)(ws + 25165824);   //  8 MB [32][2048][64]
    bf16* Vt     = (bf16*)(ws + 33554432);   //  8 MB [32][64][2048]

    conv_f32_bf16<<<2048, 256, 0, stream>>>(x, xb, 524288);
    transpose_f32_bf16<<<dim3(96, 32), 256, 0, stream>>>(Wqkv, WqkvT, EMB, 3 * EMB);
    transpose_f32_bf16<<<dim3(32, 32), 256, 0, stream>>>(Wproj, WprojT, EMB, EMB);
    gemm_qkv<<<dim3(24, 32), 256, 0, stream>>>(xb, WqkvT, bqkv, Qb, Kb, Vt);
    attn<<<512, 256, 0, stream>>>(Qb, Kb, Vt, attO);
    gemm_proj<<<dim3(8, 32), 256, 0, stream>>>(attO, WprojT, bproj, out);
}

// Round 4
// 146.721 us; speedup vs baseline: 1.1932x; 1.1932x over previous
//
#include <hip/hip_runtime.h>

typedef __bf16 bf16;
typedef __attribute__((ext_vector_type(8))) __bf16 bf16x8;
typedef __attribute__((ext_vector_type(4))) float f32x4;

#define SEQ 2048
#define EMB 1024
#define NH  16
#define DH  64

// ---------------- conversion kernels ----------------

__global__ __launch_bounds__(256) void conv_f32_bf16(const float* __restrict__ in,
                                                     bf16* __restrict__ out, int n8) {
    int i = blockIdx.x * blockDim.x + threadIdx.x;
    if (i >= n8) return;
    float4 a = ((const float4*)in)[2 * i];
    float4 b = ((const float4*)in)[2 * i + 1];
    bf16x8 o;
    o[0] = (bf16)a.x; o[1] = (bf16)a.y; o[2] = (bf16)a.z; o[3] = (bf16)a.w;
    o[4] = (bf16)b.x; o[5] = (bf16)b.y; o[6] = (bf16)b.z; o[7] = (bf16)b.w;
    ((bf16x8*)out)[i] = o;
}

// plain transpose: out[C][R] = (bf16) in[R][C]   (for Wproj)
__global__ __launch_bounds__(256) void transpose_f32_bf16(const float* __restrict__ in,
                                                          bf16* __restrict__ out,
                                                          int R, int C) {
    __shared__ float t[32][33];
    int tx = threadIdx.x & 31, ty = threadIdx.x >> 5;  // 32 x 8
    int c0 = blockIdx.x * 32, r0 = blockIdx.y * 32;
#pragma unroll
    for (int s = 0; s < 4; s++) {
        int row = ty + s * 8;
        t[row][tx] = in[(size_t)(r0 + row) * C + c0 + tx];
    }
    __syncthreads();
#pragma unroll
    for (int s = 0; s < 4; s++) {
        int row = ty + s * 8;
        out[(size_t)(c0 + row) * R + r0 + tx] = (bf16)t[tx][row];
    }
}

// permuted transpose for Wqkv: out[col'][e], col' = which*1024 + hh*64 + dd
// where original col = hh*192 + dd*3 + which
__global__ __launch_bounds__(256) void transpose_permute_qkv(const float* __restrict__ in,
                                                             bf16* __restrict__ out) {
    __shared__ float t[32][33];
    int tx = threadIdx.x & 31, ty = threadIdx.x >> 5;
    int c0 = blockIdx.x * 32, r0 = blockIdx.y * 32;   // c over 3072 cols, r over 1024 rows
#pragma unroll
    for (int s = 0; s < 4; s++) {
        int row = ty + s * 8;
        t[row][tx] = in[(size_t)(r0 + row) * 3072 + c0 + tx];
    }
    __syncthreads();
#pragma unroll
    for (int s = 0; s < 4; s++) {
        int row = ty + s * 8;
        int corig = c0 + row;
        int hh = corig / 192;
        int rem = corig - hh * 192;
        int dd = rem / 3;
        int which = rem - dd * 3;
        int colp = which * 1024 + hh * 64 + dd;
        out[(size_t)colp * EMB + r0 + tx] = (bf16)t[tx][row];
    }
}

// ---------------- GEMM core (128x128, BK=32, double-buffered) ----------------

#define BM 128
#define BN 128
#define BK 32

__device__ __forceinline__ void gload16(const bf16* g, bf16* l) {
    __builtin_amdgcn_global_load_lds((__attribute__((address_space(1))) void*)(void*)g,
                                     (__attribute__((address_space(3))) void*)l, 16, 0, 0);
}

// stage a 128x32 bf16 tile; LDS dest linear; source granule pre-swizzled
__device__ __forceinline__ void stage_tile(const bf16* src, int ld, int row0, int k0,
                                           bf16* lds, int wave, int lane) {
#pragma unroll
    for (int c = 0; c < 2; c++) {
        int chunk = wave + 4 * c;                 // 0..7, wave-uniform
        int row = chunk * 16 + (lane >> 2);
        int slot = (lane & 3) ^ ((lane >> 2) & 3);
        const bf16* g = src + (size_t)(row0 + row) * ld + k0 + slot * 8;
        gload16(g, lds + chunk * 512);
    }
}

// frag read: lane holds T[row][k=s*8..]; stored slot = s ^ (row&3)
__device__ __forceinline__ bf16x8 frag(const bf16* lds, int row, int s) {
    int slot = s ^ (row & 3);
    return *(const bf16x8*)&lds[row * BK + slot * 8];
}

__device__ __forceinline__ void gemm_mainloop(const bf16* A, const bf16* Bt, int Kdim,
                                              int m0, int n0, bf16* As, bf16* Bs,
                                              int wave, int lane, int wr, int wc,
                                              f32x4 acc[4][4]) {
    stage_tile(A, Kdim, m0, 0, As, wave, lane);
    stage_tile(Bt, Kdim, n0, 0, Bs, wave, lane);
    asm volatile("s_waitcnt vmcnt(0)" ::: "memory");
    __builtin_amdgcn_s_barrier();

    int cur = 0;
    const int iters = Kdim / BK;
    for (int it = 0; it < iters; ++it) {
        if (it + 1 < iters) {
            stage_tile(A, Kdim, m0, (it + 1) * BK, As + (cur ^ 1) * BM * BK, wave, lane);
            stage_tile(Bt, Kdim, n0, (it + 1) * BK, Bs + (cur ^ 1) * BN * BK, wave, lane);
        }
        const bf16* as = As + cur * BM * BK;
        const bf16* bs = Bs + cur * BN * BK;
        int s = lane >> 4;
        bf16x8 a[4], b[4];
#pragma unroll
        for (int i = 0; i < 4; i++)
            a[i] = frag(as, wr * 64 + i * 16 + (lane & 15), s);
#pragma unroll
        for (int j = 0; j < 4; j++)
            b[j] = frag(bs, wc * 64 + j * 16 + (lane & 15), s);
#pragma unroll
        for (int i = 0; i < 4; i++)
#pragma unroll
            for (int j = 0; j < 4; j++)
                acc[i][j] = __builtin_amdgcn_mfma_f32_16x16x32_bf16(a[i], b[j], acc[i][j], 0, 0, 0);
        asm volatile("s_waitcnt vmcnt(0)" ::: "memory");
        __builtin_amdgcn_s_barrier();
        cur ^= 1;
    }
}

// QKV projection with permuted weights: block cols n0..n0+127 are uniformly Q, K or V.
// Q/K stored row-major [bh][n][d]; V stored tiled-transposed with attn's swizzle baked:
//   V elem (bh, n, d) -> Vt[bh*32768*... : bh*131072 + (n>>6)*4096 + d*64 + swz(n&63,d)]
//   swz(nl,d) = ((nl>>3)^(d&7))*8 + (nl&7)
__global__ __launch_bounds__(256) void gemm_qkv(const bf16* __restrict__ A,
                                                const bf16* __restrict__ Bt,
                                                const float* __restrict__ bias,
                                                bf16* __restrict__ Qb, bf16* __restrict__ Kb,
                                                bf16* __restrict__ Vt) {
    __shared__ alignas(16) bf16 smem[4 * BM * BK];   // 32KB: staging, then repack tile
    bf16* As = smem;
    bf16* Bs = smem + 2 * BM * BK;
    int wave = threadIdx.x >> 6, lane = threadIdx.x & 63;
    int wr = wave >> 1, wc = wave & 1;

    // XCD swizzle: 768 blocks, 96/XCD -> 4 consecutive m-stripes per XCD
    int flat = blockIdx.y * 24 + blockIdx.x;
    int swz = (flat & 7) * 96 + (flat >> 3);
    int n0 = (swz % 24) * BN;
    int m0 = (swz / 24) * BM;

    f32x4 acc[4][4] = {};
    gemm_mainloop(A, Bt, EMB, m0, n0, As, Bs, wave, lane, wr, wc, acc);

    int which = n0 >> 10;                 // 0=Q 1=K 2=V (block-uniform)
    bool isV = (which == 2);
    char* tile = (char*)smem;

    // ---- write phase: acc + bias -> bf16 -> swizzled LDS tile ----
#pragma unroll
    for (int i = 0; i < 4; i++) {
#pragma unroll
        for (int j = 0; j < 4; j++) {
            int c = wc * 64 + j * 16 + (lane & 15);       // local col 0..127
            int hh = ((n0 + c) >> 6) & 15;
            int dd = c & 63;
            float bv = bias[hh * 192 + dd * 3 + which];
#pragma unroll
            for (int r = 0; r < 4; r++) {
                int rowL = wr * 64 + i * 16 + 4 * (lane >> 4) + r;   // local row 0..127
                float v = acc[i][j][r] + bv;
                if (which == 0) v *= 0.03125f;            // fold 1/sqrt(1024)
                int byte;
                if (!isV) byte = rowL * 256 + ((c * 2) ^ ((rowL & 7) << 4));
                else      byte = c * 256 + ((((rowL >> 3) ^ (c & 15)) << 4) + (rowL & 7) * 2);
                *(bf16*)(tile + byte) = (bf16)v;
            }
        }
    }
    __builtin_amdgcn_s_barrier();

    // ---- read phase: coalesced 16B stores ----
    int tid = threadIdx.x;
    if (!isV) {
        bf16* dst = (which == 0) ? Qb : Kb;
#pragma unroll
        for (int k = 0; k < 8; k++) {
            int f = k * 256 + tid;
            int rowL = f >> 4, ch = f & 15;
            bf16x8 val = *(const bf16x8*)(tile + rowL * 256 + ((ch ^ (rowL & 7)) << 4));
            int grow = m0 + rowL;
            int bb = grow >> 11, npos = grow & 2047;
            int cbase = ch * 8;
            int hh = ((n0 + cbase) >> 6) & 15;
            int d0 = cbase & 63;
            *(bf16x8*)(dst + (((size_t)bb * NH + hh) * SEQ + npos) * DH + d0) = val;
        }
    } else {
#pragma unroll
        for (int k = 0; k < 8; k++) {
            int f = k * 256 + tid;
            int cL = f >> 4, g = f & 15;                  // cL: local col (d-ish), g: 8-row granule
            bf16x8 val = *(const bf16x8*)(tile + cL * 256 + ((g ^ (cL & 15)) << 4));
            int grow = m0 + g * 8;
            int bb = grow >> 11, nn = grow & 2047;
            int hh = ((n0 + cL) >> 6) & 15;
            int d = cL & 63;
            int tIdx = nn >> 6, nl = nn & 63;
            size_t base = (((size_t)bb * NH + hh) * 32 + tIdx) * 4096;
            int off = d * 64 + (((nl >> 3) ^ (d & 7)) << 3);   // nl&7 == 0
            *(bf16x8*)(Vt + base + off) = val;
        }
    }
}

// proj: fp32 out + bias (stores already coalesced)
__global__ __launch_bounds__(256) void gemm_proj(const bf16* __restrict__ A,
                                                 const bf16* __restrict__ Bt,
                                                 const float* __restrict__ bias,
                                                 float* __restrict__ C) {
    __shared__ alignas(16) bf16 smem[4 * BM * BK];
    bf16* As = smem;
    bf16* Bs = smem + 2 * BM * BK;
    int wave = threadIdx.x >> 6, lane = threadIdx.x & 63;
    int wr = wave >> 1, wc = wave & 1;
    int m0 = blockIdx.y * BM, n0 = blockIdx.x * BN;
    f32x4 acc[4][4] = {};
    gemm_mainloop(A, Bt, EMB, m0, n0, As, Bs, wave, lane, wr, wc, acc);

    int m_base = m0 + wr * 64;
    int n_base = n0 + wc * 64;
#pragma unroll
    for (int i = 0; i < 4; i++) {
#pragma unroll
        for (int j = 0; j < 4; j++) {
            int col = n_base + j * 16 + (lane & 15);
            float bv = bias[col];
#pragma unroll
            for (int r = 0; r < 4; r++) {
                int row = m_base + i * 16 + 4 * (lane >> 4) + r;
                C[(size_t)row * EMB + col] = acc[i][j][r] + bv;
            }
        }
    }
}

// ---------------- attention ----------------
// Q,K: [bh][n][d] bf16 (Q pre-scaled); Vt: tiled-transposed (see gemm_qkv); O: [b][n][e]

// stage one 64-row x 128B row-major tile (K); source granule-swizzled
__device__ __forceinline__ void stage64(const bf16* gbase, int ldElems, bf16* lds,
                                        int wave, int lane) {
#pragma unroll
    for (int i = 0; i < 2; i++) {
        int c = wave * 2 + i;                       // 0..7 chunks of 1KB
        int row = c * 8 + (lane >> 3);
        int colb = (((lane & 7) ^ (lane >> 3)) << 4);
        const bf16* g = gbase + (size_t)row * ldElems + (colb >> 1);
        gload16(g, lds + c * 512);
    }
}

// stage one 8KB V tile linearly (layout+swizzle pre-baked in global)
__device__ __forceinline__ void stage64V(const bf16* tilebase, bf16* lds,
                                         int wave, int lane) {
#pragma unroll
    for (int i = 0; i < 2; i++) {
        int c = wave * 2 + i;
        gload16(tilebase + c * 512 + lane * 8, lds + c * 512);
    }
}

__global__ __launch_bounds__(256) void attn(const bf16* __restrict__ Q,
                                            const bf16* __restrict__ K,
                                            const bf16* __restrict__ Vt,
                                            bf16* __restrict__ O) {
    // XCD-aware swizzle: 512 blocks, 8 XCDs -> 64-block chunks = 4 bh per XCD
    int flat = blockIdx.x;
    int swz = (flat & 7) * 64 + (flat >> 3);
    int bh = swz >> 4;          // 16 q-blocks per bh
    int qb = swz & 15;

    int wave = threadIdx.x >> 6, lane = threadIdx.x & 63;
    int wq0 = qb * 128 + wave * 32;
    const bf16* Qg = Q + (size_t)bh * SEQ * DH;
    const bf16* Kg = K + (size_t)bh * SEQ * DH;
    const bf16* Vg = Vt + (size_t)bh * SEQ * DH;

    __shared__ alignas(16) bf16 Ks[2][64 * 64];
    __shared__ alignas(16) bf16 Vs[2][64 * 64];
    __shared__ alignas(16) bf16 Pl[4][32 * 64];
    char* pb = (char*)&Pl[wave][0];

    bf16x8 qf[2][2];
#pragma unroll
    for (int qt = 0; qt < 2; qt++)
#pragma unroll
        for (int ds = 0; ds < 2; ds++)
            qf[qt][ds] = *(const bf16x8*)(Qg + (size_t)(wq0 + qt * 16 + (lane & 15)) * DH +
                                          ds * 32 + (lane >> 4) * 8);

    f32x4 Oc[2][4] = {};
    float lsum[2][4] = {};

    stage64(Kg, DH, &Ks[0][0], wave, lane);
    stage64V(Vg, &Vs[0][0], wave, lane);
    asm volatile("s_waitcnt vmcnt(0)" ::: "memory");
    __builtin_amdgcn_s_barrier();

    int cur = 0;
    for (int it = 0; it < SEQ / 64; ++it) {
        if (it + 1 < SEQ / 64) {
            stage64(Kg + (size_t)(it + 1) * 64 * DH, DH, &Ks[cur ^ 1][0], wave, lane);
            stage64V(Vg + (size_t)(it + 1) * 4096, &Vs[cur ^ 1][0], wave, lane);
        }
        const char* kc = (const char*)&Ks[cur][0];
        const char* vc = (const char*)&Vs[cur][0];

        bf16x8 kf[4][2];
#pragma unroll
        for (int t = 0; t < 4; t++)
#pragma unroll
            for (int ds = 0; ds < 2; ds++) {
                int row = 16 * t + (lane & 15);
                int slot = (ds * 4 + (lane >> 4)) ^ (row & 7);
                kf[t][ds] = *(const bf16x8*)(kc + row * 128 + slot * 16);
            }

#pragma unroll
        for (int qt = 0; qt < 2; qt++) {
#pragma unroll
            for (int t = 0; t < 4; t++) {
                f32x4 acc = {};
#pragma unroll
                for (int ds = 0; ds < 2; ds++)
                    acc = __builtin_amdgcn_mfma_f32_16x16x32_bf16(qf[qt][ds], kf[t][ds], acc, 0, 0, 0);
#pragma unroll
                for (int r = 0; r < 4; r++) {
                    float p = __expf(acc[r]);
                    lsum[qt][r] += p;
                    int prow = qt * 16 + 4 * (lane >> 4) + r;
                    int off = (prow * 128 + (16 * t + (lane & 15)) * 2) ^ ((prow & 7) << 4);
                    *(bf16*)(pb + off) = (bf16)p;
                }
            }
        }

        bf16x8 pa[2][2];
#pragma unroll
        for (int qt = 0; qt < 2; qt++)
#pragma unroll
            for (int ms = 0; ms < 2; ms++) {
                int prow = qt * 16 + (lane & 15);
                int slot = (ms * 4 + (lane >> 4)) ^ (prow & 7);
                pa[qt][ms] = *(const bf16x8*)(pb + prow * 128 + slot * 16);
            }

#pragma unroll
        for (int dt = 0; dt < 4; dt++)
#pragma unroll
            for (int ms = 0; ms < 2; ms++) {
                int vrow = 16 * dt + (lane & 15);
                int slot = (ms * 4 + (lane >> 4)) ^ (vrow & 7);
                bf16x8 vf = *(const bf16x8*)(vc + vrow * 128 + slot * 16);
#pragma unroll
                for (int qt = 0; qt < 2; qt++)
                    Oc[qt][dt] = __builtin_amdgcn_mfma_f32_16x16x32_bf16(pa[qt][ms], vf, Oc[qt][dt], 0, 0, 0);
            }

        asm volatile("s_waitcnt vmcnt(0)" ::: "memory");
        __builtin_amdgcn_s_barrier();
        cur ^= 1;
    }

#pragma unroll
    for (int qt = 0; qt < 2; qt++)
#pragma unroll
        for (int r = 0; r < 4; r++) {
            float s = lsum[qt][r];
            s += __shfl_xor(s, 1);
            s += __shfl_xor(s, 2);
            s += __shfl_xor(s, 4);
            s += __shfl_xor(s, 8);
            lsum[qt][r] = 1.0f / s;
        }
    int bb = bh >> 4, hh = bh & 15;
#pragma unroll
    for (int qt = 0; qt < 2; qt++)
#pragma unroll
        for (int dt = 0; dt < 4; dt++)
#pragma unroll
            for (int r = 0; r < 4; r++) {
                int row = wq0 + qt * 16 + 4 * (lane >> 4) + r;
                O[((size_t)bb * SEQ + row) * EMB + hh * DH + dt * 16 + (lane & 15)] =
                    (bf16)(Oc[qt][dt][r] * lsum[qt][r]);
            }
}

// ---------------- launch ----------------

extern "C" void kernel_launch(void* const* d_in, const int* in_sizes, int n_in,
                              void* d_out, int out_size, void* d_ws, size_t ws_size,
                              hipStream_t stream) {
    const float* x     = (const float*)d_in[0];
    const float* Wqkv  = (const float*)d_in[1];
    const float* bqkv  = (const float*)d_in[2];
    const float* Wproj = (const float*)d_in[3];
    const float* bproj = (const float*)d_in[4];
    float* out = (float*)d_out;
    char* ws = (char*)d_ws;

    bf16* xb     = (bf16*)(ws + 0);          //  8 MB [4096][1024]
    bf16* attO   = xb;                       //  aliased: xb dead after gemm_qkv
    bf16* WqkvT  = (bf16*)(ws + 8388608);    //  6 MB [3072][1024] permuted
    bf16* WprojT = (bf16*)(ws + 14680064);   //  2 MB [1024][1024]
    bf16* Qb     = (bf16*)(ws + 16777216);   //  8 MB [32][2048][64]
    bf16* Kb     = (bf16*)(ws + 25165824);   //  8 MB [32][2048][64]
    bf16* Vt     = (bf16*)(ws + 33554432);   //  8 MB [32][32][64][64] tiled-swizzled

    conv_f32_bf16<<<2048, 256, 0, stream>>>(x, xb, 524288);
    transpose_permute_qkv<<<dim3(96, 32), 256, 0, stream>>>(Wqkv, WqkvT);
    transpose_f32_bf16<<<dim3(32, 32), 256, 0, stream>>>(Wproj, WprojT, EMB, EMB);
    gemm_qkv<<<dim3(24, 32), 256, 0, stream>>>(xb, WqkvT, bqkv, Qb, Kb, Vt);
    attn<<<512, 256, 0, stream>>>(Qb, Kb, Vt, attO);
    gemm_proj<<<dim3(8, 32), 256, 0, stream>>>(attO, WprojT, bproj, out);
}

// Round 6
// 146.692 us; speedup vs baseline: 1.1934x; 1.0002x over previous
//
#include <hip/hip_runtime.h>

typedef __bf16 bf16;
typedef __attribute__((ext_vector_type(8))) __bf16 bf16x8;
typedef __attribute__((ext_vector_type(4))) float f32x4;
typedef __attribute__((ext_vector_type(16))) float f32x16;
typedef unsigned int u32;
typedef __attribute__((ext_vector_type(2))) unsigned int u32x2;
typedef __attribute__((ext_vector_type(4))) unsigned int u32x4;

#define SEQ 2048
#define EMB 1024
#define NH  16
#define DH  64

// ---------------- conversion kernels ----------------

__global__ __launch_bounds__(256) void conv_f32_bf16(const float* __restrict__ in,
                                                     bf16* __restrict__ out, int n8) {
    int i = blockIdx.x * blockDim.x + threadIdx.x;
    if (i >= n8) return;
    float4 a = ((const float4*)in)[2 * i];
    float4 b = ((const float4*)in)[2 * i + 1];
    bf16x8 o;
    o[0] = (bf16)a.x; o[1] = (bf16)a.y; o[2] = (bf16)a.z; o[3] = (bf16)a.w;
    o[4] = (bf16)b.x; o[5] = (bf16)b.y; o[6] = (bf16)b.z; o[7] = (bf16)b.w;
    ((bf16x8*)out)[i] = o;
}

// plain transpose: out[C][R] = (bf16) in[R][C]   (for Wproj)
__global__ __launch_bounds__(256) void transpose_f32_bf16(const float* __restrict__ in,
                                                          bf16* __restrict__ out,
                                                          int R, int C) {
    __shared__ float t[32][33];
    int tx = threadIdx.x & 31, ty = threadIdx.x >> 5;  // 32 x 8
    int c0 = blockIdx.x * 32, r0 = blockIdx.y * 32;
#pragma unroll
    for (int s = 0; s < 4; s++) {
        int row = ty + s * 8;
        t[row][tx] = in[(size_t)(r0 + row) * C + c0 + tx];
    }
    __syncthreads();
#pragma unroll
    for (int s = 0; s < 4; s++) {
        int row = ty + s * 8;
        out[(size_t)(c0 + row) * R + r0 + tx] = (bf16)t[tx][row];
    }
}

// permuted transpose for Wqkv: out[col'][e], col' = which*1024 + hh*64 + dd
__global__ __launch_bounds__(256) void transpose_permute_qkv(const float* __restrict__ in,
                                                             bf16* __restrict__ out) {
    __shared__ float t[32][33];
    int tx = threadIdx.x & 31, ty = threadIdx.x >> 5;
    int c0 = blockIdx.x * 32, r0 = blockIdx.y * 32;
#pragma unroll
    for (int s = 0; s < 4; s++) {
        int row = ty + s * 8;
        t[row][tx] = in[(size_t)(r0 + row) * 3072 + c0 + tx];
    }
    __syncthreads();
#pragma unroll
    for (int s = 0; s < 4; s++) {
        int row = ty + s * 8;
        int corig = c0 + row;
        int hh = corig / 192;
        int rem = corig - hh * 192;
        int dd = rem / 3;
        int which = rem - dd * 3;
        int colp = which * 1024 + hh * 64 + dd;
        out[(size_t)colp * EMB + r0 + tx] = (bf16)t[tx][row];
    }
}

// ---------------- GEMM core (128x128, BK=32, double-buffered) ----------------

#define BM 128
#define BN 128
#define BK 32

__device__ __forceinline__ void gload16(const bf16* g, bf16* l) {
    __builtin_amdgcn_global_load_lds((__attribute__((address_space(1))) void*)(void*)g,
                                     (__attribute__((address_space(3))) void*)l, 16, 0, 0);
}

__device__ __forceinline__ void stage_tile(const bf16* src, int ld, int row0, int k0,
                                           bf16* lds, int wave, int lane) {
#pragma unroll
    for (int c = 0; c < 2; c++) {
        int chunk = wave + 4 * c;
        int row = chunk * 16 + (lane >> 2);
        int slot = (lane & 3) ^ ((lane >> 2) & 3);
        const bf16* g = src + (size_t)(row0 + row) * ld + k0 + slot * 8;
        gload16(g, lds + chunk * 512);
    }
}

__device__ __forceinline__ bf16x8 frag(const bf16* lds, int row, int s) {
    int slot = s ^ (row & 3);
    return *(const bf16x8*)&lds[row * BK + slot * 8];
}

__device__ __forceinline__ void gemm_mainloop(const bf16* A, const bf16* Bt, int Kdim,
                                              int m0, int n0, bf16* As, bf16* Bs,
                                              int wave, int lane, int wr, int wc,
                                              f32x4 acc[4][4]) {
    stage_tile(A, Kdim, m0, 0, As, wave, lane);
    stage_tile(Bt, Kdim, n0, 0, Bs, wave, lane);
    asm volatile("s_waitcnt vmcnt(0)" ::: "memory");
    __builtin_amdgcn_s_barrier();

    int cur = 0;
    const int iters = Kdim / BK;
    for (int it = 0; it < iters; ++it) {
        if (it + 1 < iters) {
            stage_tile(A, Kdim, m0, (it + 1) * BK, As + (cur ^ 1) * BM * BK, wave, lane);
            stage_tile(Bt, Kdim, n0, (it + 1) * BK, Bs + (cur ^ 1) * BN * BK, wave, lane);
        }
        const bf16* as = As + cur * BM * BK;
        const bf16* bs = Bs + cur * BN * BK;
        int s = lane >> 4;
        bf16x8 a[4], b[4];
#pragma unroll
        for (int i = 0; i < 4; i++)
            a[i] = frag(as, wr * 64 + i * 16 + (lane & 15), s);
#pragma unroll
        for (int j = 0; j < 4; j++)
            b[j] = frag(bs, wc * 64 + j * 16 + (lane & 15), s);
#pragma unroll
        for (int i = 0; i < 4; i++)
#pragma unroll
            for (int j = 0; j < 4; j++)
                acc[i][j] = __builtin_amdgcn_mfma_f32_16x16x32_bf16(a[i], b[j], acc[i][j], 0, 0, 0);
        asm volatile("s_waitcnt vmcnt(0)" ::: "memory");
        __builtin_amdgcn_s_barrier();
        cur ^= 1;
    }
}

// QKV projection with permuted weights; V stored tiled-swizzled
__global__ __launch_bounds__(256) void gemm_qkv(const bf16* __restrict__ A,
                                                const bf16* __restrict__ Bt,
                                                const float* __restrict__ bias,
                                                bf16* __restrict__ Qb, bf16* __restrict__ Kb,
                                                bf16* __restrict__ Vt) {
    __shared__ alignas(16) bf16 smem[4 * BM * BK];
    bf16* As = smem;
    bf16* Bs = smem + 2 * BM * BK;
    int wave = threadIdx.x >> 6, lane = threadIdx.x & 63;
    int wr = wave >> 1, wc = wave & 1;

    int flat = blockIdx.y * 24 + blockIdx.x;
    int swz = (flat & 7) * 96 + (flat >> 3);
    int n0 = (swz % 24) * BN;
    int m0 = (swz / 24) * BM;

    f32x4 acc[4][4] = {};
    gemm_mainloop(A, Bt, EMB, m0, n0, As, Bs, wave, lane, wr, wc, acc);

    int which = n0 >> 10;
    bool isV = (which == 2);
    char* tile = (char*)smem;

#pragma unroll
    for (int i = 0; i < 4; i++) {
#pragma unroll
        for (int j = 0; j < 4; j++) {
            int c = wc * 64 + j * 16 + (lane & 15);
            int hh = ((n0 + c) >> 6) & 15;
            int dd = c & 63;
            float bv = bias[hh * 192 + dd * 3 + which];
#pragma unroll
            for (int r = 0; r < 4; r++) {
                int rowL = wr * 64 + i * 16 + 4 * (lane >> 4) + r;
                float v = acc[i][j][r] + bv;
                if (which == 0) v *= 0.03125f;
                int byte;
                if (!isV) byte = rowL * 256 + ((c * 2) ^ ((rowL & 7) << 4));
                else      byte = c * 256 + ((((rowL >> 3) ^ (c & 15)) << 4) + (rowL & 7) * 2);
                *(bf16*)(tile + byte) = (bf16)v;
            }
        }
    }
    __builtin_amdgcn_s_barrier();

    int tid = threadIdx.x;
    if (!isV) {
        bf16* dst = (which == 0) ? Qb : Kb;
#pragma unroll
        for (int k = 0; k < 8; k++) {
            int f = k * 256 + tid;
            int rowL = f >> 4, ch = f & 15;
            bf16x8 val = *(const bf16x8*)(tile + rowL * 256 + ((ch ^ (rowL & 7)) << 4));
            int grow = m0 + rowL;
            int bb = grow >> 11, npos = grow & 2047;
            int cbase = ch * 8;
            int hh = ((n0 + cbase) >> 6) & 15;
            int d0 = cbase & 63;
            *(bf16x8*)(dst + (((size_t)bb * NH + hh) * SEQ + npos) * DH + d0) = val;
        }
    } else {
#pragma unroll
        for (int k = 0; k < 8; k++) {
            int f = k * 256 + tid;
            int cL = f >> 4, g = f & 15;
            bf16x8 val = *(const bf16x8*)(tile + cL * 256 + ((g ^ (cL & 15)) << 4));
            int grow = m0 + g * 8;
            int bb = grow >> 11, nn = grow & 2047;
            int hh = ((n0 + cL) >> 6) & 15;
            int d = cL & 63;
            int tIdx = nn >> 6, nl = nn & 63;
            size_t base = (((size_t)bb * NH + hh) * 32 + tIdx) * 4096;
            int off = d * 64 + (((nl >> 3) ^ (d & 7)) << 3);
            *(bf16x8*)(Vt + base + off) = val;
        }
    }
}

// proj: fp32 out + bias
__global__ __launch_bounds__(256) void gemm_proj(const bf16* __restrict__ A,
                                                 const bf16* __restrict__ Bt,
                                                 const float* __restrict__ bias,
                                                 float* __restrict__ C) {
    __shared__ alignas(16) bf16 smem[4 * BM * BK];
    bf16* As = smem;
    bf16* Bs = smem + 2 * BM * BK;
    int wave = threadIdx.x >> 6, lane = threadIdx.x & 63;
    int wr = wave >> 1, wc = wave & 1;
    int m0 = blockIdx.y * BM, n0 = blockIdx.x * BN;
    f32x4 acc[4][4] = {};
    gemm_mainloop(A, Bt, EMB, m0, n0, As, Bs, wave, lane, wr, wc, acc);

    int m_base = m0 + wr * 64;
    int n_base = n0 + wc * 64;
#pragma unroll
    for (int i = 0; i < 4; i++) {
#pragma unroll
        for (int j = 0; j < 4; j++) {
            int col = n_base + j * 16 + (lane & 15);
            float bv = bias[col];
#pragma unroll
            for (int r = 0; r < 4; r++) {
                int row = m_base + i * 16 + 4 * (lane >> 4) + r;
                C[(size_t)row * EMB + col] = acc[i][j][r] + bv;
            }
        }
    }
}

// ---------------- attention (32x32 MFMA, swapped QK^T, register softmax) ----------------
// Q,K: [bh][n][d] bf16 (Q pre-scaled); Vt: tiled-swizzled; O: [b][n][e] bf16
// 4 waves/block, 64 q-rows/wave (256/block), grid 256, KV tile 64 dbuf in LDS.
// P stays in registers in the 32x32 C/D layout; V fragments are gathered
// (2x ds_read_b64) to MATCH that layout -- no permlane/cvt_pk asm needed.

__device__ __forceinline__ void stage64(const bf16* gbase, int ldElems, bf16* lds,
                                        int wave, int lane) {
#pragma unroll
    for (int i = 0; i < 2; i++) {
        int c = wave * 2 + i;
        int row = c * 8 + (lane >> 3);
        int colb = (((lane & 7) ^ (lane >> 3)) << 4);
        const bf16* g = gbase + (size_t)row * ldElems + (colb >> 1);
        gload16(g, lds + c * 512);
    }
}

__device__ __forceinline__ void stage64V(const bf16* tilebase, bf16* lds,
                                         int wave, int lane) {
#pragma unroll
    for (int i = 0; i < 2; i++) {
        int c = wave * 2 + i;
        gload16(tilebase + c * 512 + lane * 8, lds + c * 512);
    }
}

__device__ __forceinline__ u32 pack_bf16(float lo, float hi) {
    unsigned short a = __builtin_bit_cast(unsigned short, (bf16)lo);
    unsigned short b = __builtin_bit_cast(unsigned short, (bf16)hi);
    return (u32)a | ((u32)b << 16);
}

__global__ __launch_bounds__(256, 1) void attn(const bf16* __restrict__ Q,
                                               const bf16* __restrict__ K,
                                               const bf16* __restrict__ Vt,
                                               bf16* __restrict__ O) {
    // 256 blocks, 8 XCDs -> 32-block chunks = 4 bh per XCD
    int flat = blockIdx.x;
    int swz = (flat & 7) * 32 + (flat >> 3);
    int bh = swz >> 3;          // 8 q-blocks per bh
    int qb = swz & 7;

    int wave = threadIdx.x >> 6, lane = threadIdx.x & 63;
    int l31 = lane & 31, h = lane >> 5, l7 = lane & 7;
    int qw0 = qb * 256 + wave * 64;
    const bf16* Qg = Q + (size_t)bh * SEQ * DH;
    const bf16* Kg = K + (size_t)bh * SEQ * DH;
    const bf16* Vg = Vt + (size_t)bh * SEQ * DH;

    __shared__ alignas(16) bf16 Ks[2][64 * 64];
    __shared__ alignas(16) bf16 Vs[2][64 * 64];

    // Q fragments (B-frag): qf[qt][ks] = Q[qw0+qt*32+l31][ks*16 + h*8 ..+7]
    bf16x8 qf[2][4];
#pragma unroll
    for (int qt = 0; qt < 2; qt++)
#pragma unroll
        for (int ks = 0; ks < 4; ks++)
            qf[qt][ks] = *(const bf16x8*)(Qg + (size_t)(qw0 + qt * 32 + l31) * DH +
                                          ks * 16 + h * 8);

    f32x16 Oc[2][2] = {};
    float lsum[2] = {0.f, 0.f};

    stage64(Kg, DH, &Ks[0][0], wave, lane);
    stage64V(Vg, &Vs[0][0], wave, lane);
    asm volatile("s_waitcnt vmcnt(0)" ::: "memory");
    __builtin_amdgcn_s_barrier();

    int cur = 0;
    for (int it = 0; it < SEQ / 64; ++it) {
        if (it + 1 < SEQ / 64) {
            stage64(Kg + (size_t)(it + 1) * 64 * DH, DH, &Ks[cur ^ 1][0], wave, lane);
            stage64V(Vg + (size_t)(it + 1) * 4096, &Vs[cur ^ 1][0], wave, lane);
        }
        const char* kc = (const char*)&Ks[cur][0];
        const char* vc = (const char*)&Vs[cur][0];

        // phase A: S^T = K Q^T per (T, qt); exp; pack.
        // w[qt][T][p] holds P rows {base_p+4h, base_p+1+4h} (base_p = 2(p&1)+8(p>>1))
        // at q-column l31 -- the natural 32x32 C/D layout, kept as-is.
        u32 w[2][2][8];
#pragma unroll
        for (int T = 0; T < 2; T++) {
            bf16x8 kf[4];
#pragma unroll
            for (int ks = 0; ks < 4; ks++) {
                int row = T * 32 + l31;
                int slot = (ks * 2 + h) ^ l7;
                kf[ks] = *(const bf16x8*)(kc + row * 128 + slot * 16);
            }
#pragma unroll
            for (int qt = 0; qt < 2; qt++) {
                f32x16 st = {};
#pragma unroll
                for (int ks = 0; ks < 4; ks++)
                    st = __builtin_amdgcn_mfma_f32_32x32x16_bf16(kf[ks], qf[qt][ks], st, 0, 0, 0);
#pragma unroll
                for (int p = 0; p < 8; p++) {
                    float p0 = __expf(st[2 * p]);
                    float p1 = __expf(st[2 * p + 1]);
                    lsum[qt] += p0 + p1;
                    w[qt][T][p] = pack_bf16(p0, p1);
                }
            }
        }

        // phase B: O += P @ V.  A-operand slot (h, i=2j+b) of chunk mc holds
        // P[m = mc*16 + (j<2 ? 0:8) + 4h + 2(j&1)+b]; gather V to the same map:
        // vf elems 0..3 = V[mc*16+4h+0..3][d], elems 4..7 = V[mc*16+8+4h+0..3][d].
#pragma unroll
        for (int dt = 0; dt < 2; dt++) {
            int d = dt * 32 + l31;
            const char* vrow = vc + d * 128;
#pragma unroll
            for (int mc = 0; mc < 4; mc++) {
                u32x2 vlo = *(const u32x2*)(vrow + (((mc * 2) ^ l7) << 4) + 8 * h);
                u32x2 vhi = *(const u32x2*)(vrow + (((mc * 2 + 1) ^ l7) << 4) + 8 * h);
                u32x4 vv = {vlo.x, vlo.y, vhi.x, vhi.y};
                bf16x8 vf = __builtin_bit_cast(bf16x8, vv);
#pragma unroll
                for (int qt = 0; qt < 2; qt++) {
                    u32x4 pw = {w[qt][mc >> 1][4 * (mc & 1) + 0], w[qt][mc >> 1][4 * (mc & 1) + 1],
                                w[qt][mc >> 1][4 * (mc & 1) + 2], w[qt][mc >> 1][4 * (mc & 1) + 3]};
                    bf16x8 pa = __builtin_bit_cast(bf16x8, pw);
                    Oc[qt][dt] = __builtin_amdgcn_mfma_f32_32x32x16_bf16(pa, vf, Oc[qt][dt], 0, 0, 0);
                }
            }
        }

        asm volatile("s_waitcnt vmcnt(0)" ::: "memory");
        __builtin_amdgcn_s_barrier();
        cur ^= 1;
    }

    // epilogue: rsum + scaled store
    int bb = bh >> 4, hh = bh & 15;
#pragma unroll
    for (int qt = 0; qt < 2; qt++) {
        float ls = lsum[qt] + __shfl_xor(lsum[qt], 32);
        float rinv = 1.0f / ls;        // lane holds column q = l31
#pragma unroll
        for (int reg = 0; reg < 16; reg++) {
            int qlocal = (reg & 3) + 8 * (reg >> 2) + 4 * h;
            float sc = __shfl(rinv, qlocal);
            int row = qw0 + qt * 32 + qlocal;
#pragma unroll
            for (int dt = 0; dt < 2; dt++) {
                O[((size_t)bb * SEQ + row) * EMB + hh * DH + dt * 32 + l31] =
                    (bf16)(Oc[qt][dt][reg] * sc);
            }
        }
    }
}

// ---------------- launch ----------------

extern "C" void kernel_launch(void* const* d_in, const int* in_sizes, int n_in,
                              void* d_out, int out_size, void* d_ws, size_t ws_size,
                              hipStream_t stream) {
    const float* x     = (const float*)d_in[0];
    const float* Wqkv  = (const float*)d_in[1];
    const float* bqkv  = (const float*)d_in[2];
    const float* Wproj = (const float*)d_in[3];
    const float* bproj = (const float*)d_in[4];
    float* out = (float*)d_out;
    char* ws = (char*)d_ws;

    bf16* xb     = (bf16*)(ws + 0);          //  8 MB [4096][1024]
    bf16* attO   = xb;                       //  aliased: xb dead after gemm_qkv
    bf16* WqkvT  = (bf16*)(ws + 8388608);    //  6 MB [3072][1024] permuted
    bf16* WprojT = (bf16*)(ws + 14680064);   //  2 MB [1024][1024]
    bf16* Qb     = (bf16*)(ws + 16777216);   //  8 MB [32][2048][64]
    bf16* Kb     = (bf16*)(ws + 25165824);   //  8 MB [32][2048][64]
    bf16* Vt     = (bf16*)(ws + 33554432);   //  8 MB [32][32][64][64] tiled-swizzled

    conv_f32_bf16<<<2048, 256, 0, stream>>>(x, xb, 524288);
    transpose_permute_qkv<<<dim3(96, 32), 256, 0, stream>>>(Wqkv, WqkvT);
    transpose_f32_bf16<<<dim3(32, 32), 256, 0, stream>>>(Wproj, WprojT, EMB, EMB);
    gemm_qkv<<<dim3(24, 32), 256, 0, stream>>>(xb, WqkvT, bqkv, Qb, Kb, Vt);
    attn<<<256, 256, 0, stream>>>(Qb, Kb, Vt, attO);
    gemm_proj<<<dim3(8, 32), 256, 0, stream>>>(attO, WprojT, bproj, out);
}